// Round 10
// baseline (138.088 us; speedup 1.0000x reference)
//
#include <hip/hip_runtime.h>
#include <hip/hip_bf16.h>

#define BATCH 4
#define CHAN 128
#define HGT 96
#define WID 160
#define HW (HGT * WID)
#define THREADS 512
#define TENSOR_ELEMS (BATCH * CHAN * HGT * WID)
#define WS_NEED ((size_t)TENSOR_ELEMS * 2)   // tgt NHWC bf16 only

typedef __attribute__((ext_vector_type(8))) short short8;
typedef __attribute__((ext_vector_type(4))) float float4v;

// Output channel index for displacement (dy,dx), matching _displacements(4) order.
__device__ __forceinline__ int chan_of(int dy, int dx) {
    if (dy == 0 && dx == 0) return 0;
    if (dx == 0) { int i = dy < 0 ? -dy : dy; return 1 + (i - 1) * 20 + (dy < 0 ? 0 : 1); }
    if (dy == 0) { int i = dx < 0 ? -dx : dx; return 1 + (i - 1) * 20 + (dx < 0 ? 2 : 3); }
    int i = dy < 0 ? -dy : dy;
    int j = dx < 0 ? -dx : dx;
    int s = (dy < 0) ? (dx < 0 ? 0 : 2) : (dx < 0 ? 3 : 1);
    return 1 + (i - 1) * 20 + 4 + (j - 1) * 4 + s;
}

// Packed fp32x2 -> bf16x2 (v_cvt_pk_bf16_f32).
__device__ __forceinline__ unsigned pk2(float a, float b) {
    __hip_bfloat162 h = __float22bfloat162_rn(make_float2(a, b));
    unsigned u;
    __builtin_memcpy(&u, &h, 4);
    return u;
}

union sl_u { uint4 v; short8 s; };

// ---------------------------------------------------------------------------
// Pre-pass: tgt NCHW f32 -> NHWC bf16 (R3/R4/R8/R9-verified).
// ---------------------------------------------------------------------------
__global__ __launch_bounds__(256)
void nhwc_bf16_tgt(const float* __restrict__ tgt, ushort* __restrict__ ws) {
    __shared__ unsigned s_t[64][65];
    int r = blockIdx.x;                 // 3 * 96 * 4 = 1152
    const int xb = r % 3; r /= 3;
    const int y  = r % HGT; r /= HGT;
    const int b  = r;                   // 0..3
    const int x0 = xb * 64;
    const int npx = (x0 + 64 <= WID) ? 64 : (WID - x0);   // 64 or 32

    const int t  = threadIdx.x;
    const int x1 = t & 63, cp0 = t >> 6;
    if (x1 < npx) {
        const int base = (b * CHAN * HGT + y) * WID + x0 + x1;  // channel 0
        #pragma unroll
        for (int i = 0; i < 16; ++i) {
            const int cp = cp0 + i * 4;                 // channel pair 0..63
            s_t[cp][x1] = pk2(tgt[base + (2 * cp) * HW],
                              tgt[base + (2 * cp + 1) * HW]);
        }
    }
    __syncthreads();
    const int x2 = t >> 2, g = t & 3;
    if (x2 < npx) {
        ushort* op = ws + ((size_t)(b * HGT + y) * WID + x0 + x2) * CHAN + g * 32;
        #pragma unroll
        for (int k = 0; k < 4; ++k) {
            uint4 v;
            v.x = s_t[g * 16 + k * 4 + 0][x2];
            v.y = s_t[g * 16 + k * 4 + 1][x2];
            v.z = s_t[g * 16 + k * 4 + 2][x2];
            v.w = s_t[g * 16 + k * 4 + 3][x2];
            *(uint4*)(op + k * 8) = v;
        }
    }
}

// ---------------------------------------------------------------------------
// Main kernel v10: NO B staging. B fragments are read DIRECTLY from global
// NHWC bf16 — per wave-instr the 64 lanes cover 16 fully-used 64B lines, and
// the XCD slab swizzle makes each block's tgt slab (1.97 MB bf16) L2-resident.
// This deletes the 4608-slot LDS tile, 9 DMA/thread, zero-fill, and the
// all-wave drain barrier (the suspected 20 us residual). Loads pipeline into
// the unrolled MFMA loop; OOB rows = wave-uniform skip (acc stays 0 =
// reference zero-pad); OOB cols = per-lane select. ONE barrier total.
// LDS = 22 KB epilogue buffer only.
// ---------------------------------------------------------------------------
__global__ __launch_bounds__(THREADS, 4)
void cost_volume_direct(const float* __restrict__ src,
                        const ushort* __restrict__ tgtT,
                        float* __restrict__ out) {
    __shared__ float s_o[81 * 68];      // 22032 B
    __shared__ int s_tab[81];           // cix -> oc*HW

    const int tid  = threadIdx.x;
    const int wv   = tid >> 6;        // 0..7
    const int wvy  = wv & 3;          // y sub-row
    const int wvd  = wv >> 2;         // 0: dy 0-3, 1: dy 4-8
    const int lane = tid & 63;
    const int q    = lane >> 4;
    const int ln   = lane & 15;

    // XCD-affinity swizzle: blockIdx%8 -> (batch, y-half) slab.
    const int w    = blockIdx.x;      // 0..959
    const int slab = w & 7;
    const int b    = slab >> 1;
    const int yh   = slab & 1;
    const int t    = w >> 3;          // 0..119
    const int x0   = (t % 10) * 16;
    const int y0   = yh * 48 + (t / 10) * 4;

    if (tid < 81) s_tab[tid] = chan_of(tid / 9 - 4, tid % 9 - 4) * HW;

    // ---- A (NCHW f32): one-exposure 32 loads, then convert (R9-verified) ----
    const int y = y0 + wvy;
    const int sbase = (b * CHAN * HGT + y) * WID + x0 + ln + q * 8 * HW;
    float apay[32];
    #pragma unroll
    for (int ks = 0; ks < 4; ++ks)
        #pragma unroll
        for (int j = 0; j < 8; ++j)
            apay[ks * 8 + j] = src[sbase + (ks * 32 + j) * HW];
    short8 afr[4];
    #pragma unroll
    for (int ks = 0; ks < 4; ++ks) {
        sl_u f;
        f.v.x = pk2(apay[ks * 8 + 0], apay[ks * 8 + 1]);
        f.v.y = pk2(apay[ks * 8 + 2], apay[ks * 8 + 3]);
        f.v.z = pk2(apay[ks * 8 + 4], apay[ks * 8 + 5]);
        f.v.w = pk2(apay[ks * 8 + 6], apay[ks * 8 + 7]);
        afr[ks] = f.s;
    }

    // ---- compute: direct-global B fragments + MFMA ----
    const ushort* tb8 = tgtT + (size_t)b * HGT * WID * CHAN;
    const int gx0 = x0 - 4 + ln;           // nt=0 pixel x
    const int gx1 = x0 + 12 + ln;          // nt=1 pixel x
    const bool cok0 = (unsigned)gx0 < (unsigned)WID;
    const bool cok1 = (unsigned)gx1 < (unsigned)WID;
    const short8 zf = (short8){0, 0, 0, 0, 0, 0, 0, 0};

    float4v aa0[5], aa1[5];
    const int ndd = wvd ? 5 : 4;
    #pragma unroll
    for (int dd = 0; dd < 5; ++dd) {
        if (dd >= ndd) break;
        const int dyi = wvd ? dd + 4 : dd;
        const int gr  = y0 - 4 + wvy + dyi;           // wave-uniform tgt row
        float4v a0 = (float4v){0.f, 0.f, 0.f, 0.f};
        float4v a1 = (float4v){0.f, 0.f, 0.f, 0.f};
        if ((unsigned)gr < (unsigned)HGT) {           // wave-uniform branch
            const ushort* rp = tb8 + (size_t)gr * WID * CHAN;
            const ushort* p0 = rp + gx0 * CHAN + q * 8;
            const ushort* p1 = rp + gx1 * CHAN + q * 8;
            short8 bf0[4], bf1[4];
            #pragma unroll
            for (int ks = 0; ks < 4; ++ks)
                bf0[ks] = cok0 ? *(const short8*)(p0 + ks * 32) : zf;
            #pragma unroll
            for (int ks = 0; ks < 4; ++ks)
                bf1[ks] = cok1 ? *(const short8*)(p1 + ks * 32) : zf;
            #pragma unroll
            for (int ks = 0; ks < 4; ++ks)
                a0 = __builtin_amdgcn_mfma_f32_16x16x32_bf16(afr[ks], bf0[ks], a0, 0, 0, 0);
            #pragma unroll
            for (int ks = 0; ks < 4; ++ks)
                a1 = __builtin_amdgcn_mfma_f32_16x16x32_bf16(afr[ks], bf1[ks], a1, 0, 0, 0);
        }
        aa0[dd] = a0;
        aa1[dd] = a1;
    }

    // ---- banded accs -> LDS [81 ch][68] f32 (verified epilogue) ----
    const float inv = 1.0f / 81.0f;
    #pragma unroll
    for (int dd = 0; dd < 5; ++dd) {
        if (dd >= ndd) break;
        const int dyi = wvd ? dd + 4 : dd;
        #pragma unroll
        for (int reg = 0; reg < 4; ++reg) {
            const int m = q * 4 + reg;
            const int t0x = ln - m;             // dx+4 for nt=0
            if ((unsigned)t0x <= 8u)
                s_o[(dyi * 9 + t0x) * 68 + wvy * 16 + m] = aa0[dd][reg] * inv;
            const int t1x = ln + 16 - m;        // dx+4 for nt=1
            if ((unsigned)t1x <= 8u)
                s_o[(dyi * 9 + t1x) * 68 + wvy * 16 + m] = aa1[dd][reg] * inv;
        }
    }
    __syncthreads();   // the ONLY barrier

    // ---- store: 1296 float4 tasks; lanes span x within one (ch,y) row ----
    const size_t ob = (size_t)b * 81 * HW + (size_t)y0 * WID + x0;
    #pragma unroll
    for (int it = 0; it < 3; ++it) {
        const int v = it * THREADS + tid;
        if (v < 1296) {
            const int xq  = v & 3;
            const int row = v >> 2;           // 0..323 = cix*4 + yy
            const int cix = row >> 2;
            const int yy  = row & 3;
            float4v val = *(const float4v*)&s_o[cix * 68 + yy * 16 + xq * 4];
            *(float4v*)&out[ob + s_tab[cix] + yy * WID + xq * 4] = val;
        }
    }
}

// ---------------------------------------------------------------------------
// Fallback (ws too small): R5 fused single kernel (verified passing).
// ---------------------------------------------------------------------------
#define FST_DECODE(TAG, U)                                                    \
    const int u##TAG   = (U);                                                 \
    const int xq##TAG  = u##TAG % 6;                                          \
    const int r6##TAG  = u##TAG / 6;                                          \
    const int oct##TAG = r6##TAG & 15;                                        \
    const int row##TAG = r6##TAG >> 4;                                        \
    const int gr##TAG  = y0 - 4 + row##TAG;                                   \
    const int gx##TAG  = x0 - 4 + xq##TAG * 4;                                \
    const bool ok##TAG = ((unsigned)gr##TAG < (unsigned)HGT) &&               \
                         ((unsigned)gx##TAG < (unsigned)WID);                 \
    const int ga##TAG  = tb + (oct##TAG * 8 * HGT + gr##TAG) * WID + gx##TAG;

#define FST_ISSUE(TAG, COND)                                                  \
    _Pragma("unroll")                                                         \
    for (int j = 0; j < 8; ++j)                                               \
        p##TAG[j] = (COND) ? *(const float4v*)(tgt + ga##TAG + j * HW)        \
                           : (float4v){0.f, 0.f, 0.f, 0.f};

#define FST_WRITE(TAG)                                                        \
    _Pragma("unroll")                                                         \
    for (int i = 0; i < 4; ++i) {                                             \
        const int xl = xq##TAG * 4 + i;                                       \
        uint4 val;                                                            \
        val.x = pk2(p##TAG[0][i], p##TAG[1][i]);                              \
        val.y = pk2(p##TAG[2][i], p##TAG[3][i]);                              \
        val.z = pk2(p##TAG[4][i], p##TAG[5][i]);                              \
        val.w = pk2(p##TAG[6][i], p##TAG[7][i]);                              \
        s_b[(row##TAG * 24 + xl) * 16 + (oct##TAG ^ (xl & 15))] = val;        \
    }

__global__ __launch_bounds__(THREADS, 4)
void cost_volume_fused(const float* __restrict__ src,
                       const float* __restrict__ tgt,
                       float* __restrict__ out) {
    __shared__ __align__(16) uint4 s_b[4736];
    __shared__ int s_tab[81];

    const int tid  = threadIdx.x;
    const int wv   = tid >> 6;
    const int wvy  = wv & 3;
    const int wvd  = wv >> 2;
    const int lane = tid & 63;
    const int q    = lane >> 4;
    const int ln   = lane & 15;

    const int w    = blockIdx.x;
    const int slab = w & 7;
    const int b    = slab >> 1;
    const int yh   = slab & 1;
    const int t    = w >> 3;
    const int x0   = (t % 10) * 16;
    const int y0   = yh * 48 + (t / 10) * 4;

    if (tid < 81) s_tab[tid] = chan_of(tid / 9 - 4, tid % 9 - 4) * HW;

    const int tb = b * CHAN * HGT * WID;

    FST_DECODE(0, tid)
    FST_DECODE(1, tid + 512)
    FST_DECODE(2, tid + 1024)
    const bool has2 = tid < 128;

    float4v p0[8], p1[8], p2[8];
    FST_ISSUE(0, ok0)

    const int y = y0 + wvy;
    const int sbase = (b * CHAN * HGT + y) * WID + x0 + ln + q * 8 * HW;
    float apay[32];
    #pragma unroll
    for (int ks = 0; ks < 4; ++ks)
        #pragma unroll
        for (int j = 0; j < 8; ++j)
            apay[ks * 8 + j] = src[sbase + (ks * 32 + j) * HW];

    FST_ISSUE(1, ok1)
    FST_WRITE(0)
    FST_ISSUE(2, has2 && ok2)
    short8 afr[4];
    #pragma unroll
    for (int ks = 0; ks < 4; ++ks) {
        sl_u f;
        f.v.x = pk2(apay[ks * 8 + 0], apay[ks * 8 + 1]);
        f.v.y = pk2(apay[ks * 8 + 2], apay[ks * 8 + 3]);
        f.v.z = pk2(apay[ks * 8 + 4], apay[ks * 8 + 5]);
        f.v.w = pk2(apay[ks * 8 + 6], apay[ks * 8 + 7]);
        afr[ks] = f.s;
    }
    FST_WRITE(1)
    if (has2) { FST_WRITE(2) }

    __syncthreads();

    float4v aa0[5], aa1[5];
    #define COMPUTE_DY(DD, DYI)                                               \
        {                                                                     \
            const int rr = wvy + (DYI);                                       \
            float4v a0 = (float4v){0.f, 0.f, 0.f, 0.f};                       \
            float4v a1 = (float4v){0.f, 0.f, 0.f, 0.f};                       \
            _Pragma("unroll")                                                 \
            for (int ks = 0; ks < 4; ++ks) {                                  \
                sl_u b0;                                                      \
                b0.v = s_b[(rr * 24 + ln) * 16 + ((q + ks * 4) ^ ln)];        \
                a0 = __builtin_amdgcn_mfma_f32_16x16x32_bf16(afr[ks], b0.s, a0, 0, 0, 0); \
            }                                                                 \
            _Pragma("unroll")                                                 \
            for (int ks = 0; ks < 4; ++ks) {                                  \
                sl_u b1;                                                      \
                b1.v = s_b[(rr * 24 + 16 + ln) * 16 + ((q + ks * 4) ^ ln)];   \
                a1 = __builtin_amdgcn_mfma_f32_16x16x32_bf16(afr[ks], b1.s, a1, 0, 0, 0); \
            }                                                                 \
            aa0[DD] = a0; aa1[DD] = a1;                                       \
        }
    if (wvd == 0) {
        #pragma unroll
        for (int dd = 0; dd < 4; ++dd) COMPUTE_DY(dd, dd)
    } else {
        #pragma unroll
        for (int dd = 0; dd < 5; ++dd) COMPUTE_DY(dd, dd + 4)
    }

    __syncthreads();

    float* s_o = (float*)s_b;
    const float inv = 1.0f / 81.0f;
    #define EPI_DY(DD, DYI)                                                   \
        _Pragma("unroll")                                                     \
        for (int reg = 0; reg < 4; ++reg) {                                   \
            const int m = q * 4 + reg;                                        \
            const int t0x = ln - m;                                           \
            if ((unsigned)t0x <= 8u)                                          \
                s_o[((DYI) * 9 + t0x) * 68 + wvy * 16 + m] = aa0[DD][reg] * inv; \
            const int t1x = ln + 16 - m;                                      \
            if ((unsigned)t1x <= 8u)                                          \
                s_o[((DYI) * 9 + t1x) * 68 + wvy * 16 + m] = aa1[DD][reg] * inv; \
        }
    if (wvd == 0) {
        #pragma unroll
        for (int dd = 0; dd < 4; ++dd) EPI_DY(dd, dd)
    } else {
        #pragma unroll
        for (int dd = 0; dd < 5; ++dd) EPI_DY(dd, dd + 4)
    }
    __syncthreads();

    const size_t ob = (size_t)b * 81 * HW + (size_t)y0 * WID + x0;
    #pragma unroll
    for (int it = 0; it < 3; ++it) {
        const int v = it * THREADS + tid;
        if (v < 1296) {
            const int xq  = v & 3;
            const int row = v >> 2;
            const int cix = row >> 2;
            const int yy  = row & 3;
            float4v val = *(const float4v*)&s_o[cix * 68 + yy * 16 + xq * 4];
            *(float4v*)&out[ob + s_tab[cix] + yy * WID + xq * 4] = val;
        }
    }
}

extern "C" void kernel_launch(void* const* d_in, const int* in_sizes, int n_in,
                              void* d_out, int out_size, void* d_ws, size_t ws_size,
                              hipStream_t stream) {
    const float* src = (const float*)d_in[0];
    const float* tgt = (const float*)d_in[1];
    float* out = (float*)d_out;
    if (d_ws && ws_size >= WS_NEED) {
        ushort* ws = (ushort*)d_ws;
        nhwc_bf16_tgt<<<dim3(1152, 1, 1), dim3(256, 1, 1), 0, stream>>>(tgt, ws);
        cost_volume_direct<<<dim3(960, 1, 1), dim3(THREADS, 1, 1), 0, stream>>>(src, ws, out);
    } else {
        cost_volume_fused<<<dim3(960, 1, 1), dim3(THREADS, 1, 1), 0, stream>>>(src, tgt, out);
    }
}

// Round 11
// 114.408 us; speedup vs baseline: 1.2070x; 1.2070x over previous
//
#include <hip/hip_runtime.h>
#include <hip/hip_bf16.h>

#define BATCH 4
#define CHAN 128
#define HGT 96
#define WID 160
#define HW (HGT * WID)
#define THREADS 512

typedef __attribute__((ext_vector_type(8))) short short8;
typedef __attribute__((ext_vector_type(4))) float float4v;

// Output channel index for displacement (dy,dx), matching _displacements(4) order.
__device__ __forceinline__ int chan_of(int dy, int dx) {
    if (dy == 0 && dx == 0) return 0;
    if (dx == 0) { int i = dy < 0 ? -dy : dy; return 1 + (i - 1) * 20 + (dy < 0 ? 0 : 1); }
    if (dy == 0) { int i = dx < 0 ? -dx : dx; return 1 + (i - 1) * 20 + (dx < 0 ? 2 : 3); }
    int i = dy < 0 ? -dy : dy;
    int j = dx < 0 ? -dx : dx;
    int s = (dy < 0) ? (dx < 0 ? 0 : 2) : (dx < 0 ? 3 : 1);
    return 1 + (i - 1) * 20 + 4 + (j - 1) * 4 + s;
}

// Packed fp32x2 -> bf16x2 (v_cvt_pk_bf16_f32).
__device__ __forceinline__ unsigned pk2(float a, float b) {
    __hip_bfloat162 h = __float22bfloat162_rn(make_float2(a, b));
    unsigned u;
    __builtin_memcpy(&u, &h, 4);
    return u;
}

union sl_u { uint4 v; short8 s; };

// Staging task = (row, oct, xq): 8 float4 loads (channels oct*8..+7, 4 px each)
// -> 4 swizzled LDS slots. 12 rows * 16 oct * 6 xq = 1152 tasks.
// Bank swizzle: slot j = oct ^ (x&15) ^ ((x>>4)<<3). The ^((x>>4)<<3) term
// fixes R5's measured 1.55M write conflicts (xq0/xq4 share x&15 -> same
// bank-quad); reads at x=16+ln apply the matching ^8.
#define FST_DECODE(TAG, U)                                                    \
    const int u##TAG   = (U);                                                 \
    const int xq##TAG  = u##TAG % 6;                                          \
    const int r6##TAG  = u##TAG / 6;                                          \
    const int oct##TAG = r6##TAG & 15;                                        \
    const int row##TAG = r6##TAG >> 4;     /* 0..11 */                        \
    const int gr##TAG  = y0 - 4 + row##TAG;                                   \
    const int gx##TAG  = x0 - 4 + xq##TAG * 4;     /* 16B aligned */          \
    const bool ok##TAG = ((unsigned)gr##TAG < (unsigned)HGT) &&               \
                         ((unsigned)gx##TAG < (unsigned)WID);                 \
    const int ga##TAG  = tb + (oct##TAG * 8 * HGT + gr##TAG) * WID + gx##TAG;

#define FST_ISSUE(TAG, COND)                                                  \
    _Pragma("unroll")                                                         \
    for (int j = 0; j < 8; ++j)                                               \
        p##TAG[j] = (COND) ? *(const float4v*)(tgt + ga##TAG + j * HW)        \
                           : (float4v){0.f, 0.f, 0.f, 0.f};

#define FST_WRITE(TAG)                                                        \
    _Pragma("unroll")                                                         \
    for (int i = 0; i < 4; ++i) {                                             \
        const int xl = xq##TAG * 4 + i;                                       \
        uint4 val;                                                            \
        val.x = pk2(p##TAG[0][i], p##TAG[1][i]);                              \
        val.y = pk2(p##TAG[2][i], p##TAG[3][i]);                              \
        val.z = pk2(p##TAG[4][i], p##TAG[5][i]);                              \
        val.w = pk2(p##TAG[6][i], p##TAG[7][i]);                              \
        s_b[(row##TAG * 24 + xl) * 16 +                                       \
            (oct##TAG ^ (xl & 15) ^ ((xl >> 4) << 3))] = val;                 \
    }

// One dy-row of the verified MFMA core. nt=0 reads x=ln (<16, swizzle term 0);
// nt=1 reads x=16+ln -> extra ^8 to match the staging swizzle.
#define COMPUTE_DY(DD, DYI)                                                   \
    {                                                                         \
        const int rr = wvy + (DYI);                                           \
        float4v a0 = (float4v){0.f, 0.f, 0.f, 0.f};                           \
        float4v a1 = (float4v){0.f, 0.f, 0.f, 0.f};                           \
        _Pragma("unroll")                                                     \
        for (int ks = 0; ks < 4; ++ks) {                                      \
            sl_u b0;                                                          \
            b0.v = s_b[(rr * 24 + ln) * 16 + ((q + ks * 4) ^ ln)];            \
            a0 = __builtin_amdgcn_mfma_f32_16x16x32_bf16(afr[ks], b0.s, a0, 0, 0, 0); \
        }                                                                     \
        _Pragma("unroll")                                                     \
        for (int ks = 0; ks < 4; ++ks) {                                      \
            sl_u b1;                                                          \
            b1.v = s_b[(rr * 24 + 16 + ln) * 16 + (((q + ks * 4) ^ ln) ^ 8)]; \
            a1 = __builtin_amdgcn_mfma_f32_16x16x32_bf16(afr[ks], b1.s, a1, 0, 0, 0); \
        }                                                                     \
        aa0[DD] = a0; aa1[DD] = a1;                                           \
    }

#define EPI_DY(DD, DYI)                                                       \
    _Pragma("unroll")                                                         \
    for (int reg = 0; reg < 4; ++reg) {                                       \
        const int m = q * 4 + reg;                                            \
        const int t0x = ln - m;             /* dx+4 for nt=0 */               \
        if ((unsigned)t0x <= 8u)                                              \
            s_o[((DYI) * 9 + t0x) * 68 + wvy * 16 + m] = aa0[DD][reg] * inv;  \
        const int t1x = ln + 16 - m;        /* dx+4 for nt=1 */               \
        if ((unsigned)t1x <= 8u)                                              \
            s_o[((DYI) * 9 + t1x) * 68 + wvy * 16 + m] = aa1[DD][reg] * inv;  \
    }

// ---------------------------------------------------------------------------
// Fused single kernel (no workspace, traffic floor 83 MB): R5 structure with
// the spill fixed. (1) launch_bounds(512,2): VGPR cap 256 so the ~160-200 VGPR
// staging payload FITS (R5's cap-128 forced scratch; R10 proved spill = the
// invisible 2-3x). (2) sched_barrier(0) fences pin issue-regions so the
// compiler cannot sink loads to their uses (its serializing heuristic);
// partial vmcnt waits then overlap t0|A|t1|t2 naturally. (3) staging bank-
// swizzle fixed (^((x>>4)<<3)). Accumulators in STATIC wvd-branch (rule #20).
// ---------------------------------------------------------------------------
__global__ __launch_bounds__(THREADS, 2)
void cost_volume_fused(const float* __restrict__ src,
                       const float* __restrict__ tgt,
                       float* __restrict__ out) {
    // 12*24*16 = 4608 slots + 128 pad (nt=1 band-masked reads at x<=31 touch
    // them; their products land only in masked-off n-columns).
    __shared__ __align__(16) uint4 s_b[4736];   // 75776 B
    __shared__ int s_tab[81];                   // cix -> oc*HW

    const int tid  = threadIdx.x;
    const int wv   = tid >> 6;        // 0..7
    const int wvy  = wv & 3;          // y sub-row
    const int wvd  = wv >> 2;         // 0: dy 0-3, 1: dy 4-8
    const int lane = tid & 63;
    const int q    = lane >> 4;
    const int ln   = lane & 15;

    // XCD-affinity swizzle: blockIdx%8 -> (batch, y-half) slab.
    const int w    = blockIdx.x;      // 0..959
    const int slab = w & 7;
    const int b    = slab >> 1;
    const int yh   = slab & 1;
    const int t    = w >> 3;          // 0..119
    const int x0   = (t % 10) * 16;
    const int y0   = yh * 48 + (t / 10) * 4;

    if (tid < 81) s_tab[tid] = chan_of(tid / 9 - 4, tid % 9 - 4) * HW;

    const int tb = b * CHAN * HGT * WID;

    FST_DECODE(0, tid)
    FST_DECODE(1, tid + 512)
    FST_DECODE(2, tid + 1024)
    const bool has2 = tid < 128;

    float4v p0[8], p1[8], p2[8];

    // ---- region 1: issue t0 | A | t1 (48 loads in flight, no uses) ----
    FST_ISSUE(0, ok0)

    const int y = y0 + wvy;
    const int sbase = (b * CHAN * HGT + y) * WID + x0 + ln + q * 8 * HW;
    float apay[32];
    #pragma unroll
    for (int ks = 0; ks < 4; ++ks)
        #pragma unroll
        for (int j = 0; j < 8; ++j)
            apay[ks * 8 + j] = src[sbase + (ks * 32 + j) * HW];

    FST_ISSUE(1, ok1)
    __builtin_amdgcn_sched_barrier(0);   // loads may not sink below this

    // ---- region 2: consume t0 (waits oldest 8 only), issue t2 ----
    FST_WRITE(0)
    FST_ISSUE(2, has2 && ok2)
    __builtin_amdgcn_sched_barrier(0);

    // ---- region 3: consume A (t1/t2 stay in flight), then t1 ----
    short8 afr[4];
    #pragma unroll
    for (int ks = 0; ks < 4; ++ks) {
        sl_u f;
        f.v.x = pk2(apay[ks * 8 + 0], apay[ks * 8 + 1]);
        f.v.y = pk2(apay[ks * 8 + 2], apay[ks * 8 + 3]);
        f.v.z = pk2(apay[ks * 8 + 4], apay[ks * 8 + 5]);
        f.v.w = pk2(apay[ks * 8 + 6], apay[ks * 8 + 7]);
        afr[ks] = f.s;
    }
    FST_WRITE(1)
    __builtin_amdgcn_sched_barrier(0);

    // ---- region 4: consume t2, barrier ----
    if (has2) { FST_WRITE(2) }
    __builtin_amdgcn_sched_barrier(0);
    __syncthreads();

    // ---- compute: this wave's 4 or 5 dys x (8 ds_read_b128 + 8 MFMA) ----
    float4v aa0[5], aa1[5];
    if (wvd == 0) {
        #pragma unroll
        for (int dd = 0; dd < 4; ++dd) COMPUTE_DY(dd, dd)
    } else {
        #pragma unroll
        for (int dd = 0; dd < 5; ++dd) COMPUTE_DY(dd, dd + 4)
    }

    __syncthreads();   // all s_b reads done -> safe to overlay s_o

    // ---- banded accs -> LDS [81 ch][68] f32 ----
    float* s_o = (float*)s_b;
    const float inv = 1.0f / 81.0f;
    if (wvd == 0) {
        #pragma unroll
        for (int dd = 0; dd < 4; ++dd) EPI_DY(dd, dd)
    } else {
        #pragma unroll
        for (int dd = 0; dd < 5; ++dd) EPI_DY(dd, dd + 4)
    }
    __syncthreads();

    // ---- store: 1296 float4 tasks; lanes span x within one (ch,y) row ----
    const size_t ob = (size_t)b * 81 * HW + (size_t)y0 * WID + x0;
    #pragma unroll
    for (int it = 0; it < 3; ++it) {
        const int v = it * THREADS + tid;
        if (v < 1296) {
            const int xq  = v & 3;
            const int row = v >> 2;           // 0..323 = cix*4 + yy
            const int cix = row >> 2;
            const int yy  = row & 3;
            float4v val = *(const float4v*)&s_o[cix * 68 + yy * 16 + xq * 4];
            *(float4v*)&out[ob + s_tab[cix] + yy * WID + xq * 4] = val;
        }
    }
}

extern "C" void kernel_launch(void* const* d_in, const int* in_sizes, int n_in,
                              void* d_out, int out_size, void* d_ws, size_t ws_size,
                              hipStream_t stream) {
    const float* src = (const float*)d_in[0];
    const float* tgt = (const float*)d_in[1];
    float* out = (float*)d_out;
    cost_volume_fused<<<dim3(960, 1, 1), dim3(THREADS, 1, 1), 0, stream>>>(src, tgt, out);
}